// Round 6
// baseline (235.955 us; speedup 1.0000x reference)
//
#include <hip/hip_runtime.h>
#include <hip/hip_cooperative_groups.h>

namespace cg = cooperative_groups;

// FullAttention: O[b,l,h,d] = softmax_s( scale * Q[b,l,h,:]·K[b,s,h,:] ) @ V[b,s,h,:]
// B=4, L=S=2048, H=8, E=D=64, fp32 in/out, bf16 MFMA compute.
// R15: R14 falsified the occupancy lever (waves/SIMD 2->2.6, attn only -2%): attn
//      plateaus ~59-62us. The dominant term is NON-attn time: dur_us - attn ~= 90us
//      in every round, while prep+combine model at ~21us -> ~70us of multi-kernel
//      overhead. This round: ONE cooperative kernel (prep -> grid.sync -> attn,
//      splits=1 so combine + num_ws vanish entirely). grid 512 = 2 blocks/CU
//      (LDS 32KB -> 5/CU, launch_bounds(256,2)) so cooperative validation passes.
//      XCD pinning survives: all task strides are multiples of 8, task%8 == bid%8.
//      FALLBACK: if hipLaunchCooperativeKernel errors (capture-unsupported etc.),
//      launch the proven R14 3-kernel path -> worst case == status quo (~152us).
//      Predictions: fused dispatch ~72-85us; dur_us ~90-105 if overhead was
//      inter-kernel; ~150 = null (harness-fixed cost); 3 dispatches = coop rejected.

#define B_ 4
#define L_ 2048
#define S_ 2048
#define H_ 8

#define NUMSZ (B_ * L_ * H_ * 64)   // 4194304 floats
#define LSZ (B_ * L_ * H_)          // 65536 floats
#define KVELEM (B_ * H_ * S_ * 64)  // 4194304 bf16 per buffer
#define TILE_ELEMS 2048             // one 32-s tile = 4 KB

typedef __attribute__((ext_vector_type(8))) __bf16 bf16x8;
typedef __attribute__((ext_vector_type(4))) __bf16 bf16x4;
typedef __attribute__((ext_vector_type(16))) float floatx16;

union BF4U { bf16x4 v; uint2 u; };
union BF8U { bf16x8 v; uint4 u; };

__device__ __forceinline__ void async_load16(const void* g, void* l) {
  __builtin_amdgcn_global_load_lds(
      (const __attribute__((address_space(1))) unsigned int*)g,
      (__attribute__((address_space(3))) unsigned int*)l, 16, 0, 0);
}

__device__ __forceinline__ bf16x8 cvt8(float4 a, float4 b) {
  bf16x8 r;
  r[0] = (__bf16)a.x; r[1] = (__bf16)a.y; r[2] = (__bf16)a.z; r[3] = (__bf16)a.w;
  r[4] = (__bf16)b.x; r[5] = (__bf16)b.y; r[6] = (__bf16)b.z; r[7] = (__bf16)b.w;
  return r;
}

// max-free softmax on one 32x32 score block + in-register C->B transform
// (validated R5-R7). Outputs the two PV B-fragments (s-chunks 0,1).
__device__ __forceinline__ void softmax_pb(const floatx16& sc, int h32, float& l,
                                           bf16x8& pB0v, bf16x8& pB1v) {
  BF4U pg[4];
#pragma unroll
  for (int g = 0; g < 4; ++g) {
    float p0 = __builtin_amdgcn_exp2f(sc[4 * g + 0]);
    float p1 = __builtin_amdgcn_exp2f(sc[4 * g + 1]);
    float p2 = __builtin_amdgcn_exp2f(sc[4 * g + 2]);
    float p3 = __builtin_amdgcn_exp2f(sc[4 * g + 3]);
    l += (p0 + p1) + (p2 + p3);
    pg[g].v = (bf16x4){(__bf16)p0, (__bf16)p1, (__bf16)p2, (__bf16)p3};
  }
  uint2 sendA = h32 ? pg[0].u : pg[1].u;
  uint2 sendB = h32 ? pg[2].u : pg[3].u;
  uint2 recvA, recvB;
  recvA.x = __shfl_xor((int)sendA.x, 32);
  recvA.y = __shfl_xor((int)sendA.y, 32);
  recvB.x = __shfl_xor((int)sendB.x, 32);
  recvB.y = __shfl_xor((int)sendB.y, 32);
  BF8U pB0, pB1;
  if (h32 == 0) {
    pB0.u = (uint4){pg[0].u.x, pg[0].u.y, recvA.x, recvA.y};
    pB1.u = (uint4){pg[2].u.x, pg[2].u.y, recvB.x, recvB.y};
  } else {
    pB0.u = (uint4){recvA.x, recvA.y, pg[1].u.x, pg[1].u.y};
    pB1.u = (uint4){recvB.x, recvB.y, pg[3].u.x, pg[3].u.y};
  }
  pB0v = pB0.v;
  pB1v = pB1.v;
}

// ---- prep task: one 32-s tile of K,V fp32 -> bf16 swizzled 4KB tiles.
// XCD-pinned decode: xcd = task&7 owns (b,h) pairs [4*xcd, 4*xcd+3].
// Vs must be >= 8KB of LDS scratch. Ends with __syncthreads (loop-safe).
__device__ __forceinline__ void prep_task(int task, const float* __restrict__ K,
                                          const float* __restrict__ V,
                                          __bf16* __restrict__ Kb,
                                          __bf16* __restrict__ Vb, float* Vs) {
  const int xcd = task & 7;
  const int idx = task >> 3;              // 0..255 per XCD
  const int pair = xcd * 4 + (idx >> 6);  // (b*8+h), 4 pairs per XCD
  const int tile = idx & 63;
  const int h = pair & 7;
  const int b = pair >> 3;
  const int obid = pair * 64 + tile;
  const int s0 = tile * 32;
  const int i = threadIdx.x;

  {
    const int s = i >> 3, cp = i & 7;
    const int e0 = 8 * (cp ^ (s & 7));
    const float* src = K + (((size_t)(b * S_ + s0 + s) * H_ + h) * 64 + e0);
    float4 a = *(const float4*)src;
    float4 bb = *(const float4*)(src + 4);
    *(bf16x8*)(Kb + (size_t)obid * TILE_ELEMS + i * 8) = cvt8(a, bb);
  }
  {
    const int s = i >> 3, d0 = (i & 7) * 8;
    const float* src = V + (((size_t)(b * S_ + s0 + s) * H_ + h) * 64 + d0);
    float4 a = *(const float4*)src;
    float4 bb = *(const float4*)(src + 4);
    *(float4*)&Vs[s * 64 + d0] = a;
    *(float4*)&Vs[s * 64 + d0 + 4] = bb;
  }
  __syncthreads();
  {
    const int Ll = i >> 3, cp = i & 7;
    const int ci = cp ^ (Ll & 7);
    const int d = 2 * Ll + (ci >> 2);
    const int ch = ci & 3;
    BF8U o;
#pragma unroll
    for (int j = 0; j < 8; ++j) o.v[j] = (__bf16)Vs[(8 * ch + j) * 64 + d];
    *(bf16x8*)(Vb + (size_t)obid * TILE_ELEMS + i * 8) = o.v;
  }
  __syncthreads();  // next task may overwrite Vs
}

// ---- attn task: 128 q-rows (4 waves x 32 q), one (b,h,split) chunk of S.
// KtB/VtB: 2 x 2 x TILE_ELEMS bf16 LDS double-buffers.
__device__ __forceinline__ void attn_task(int task, int splits,
                                          const float* __restrict__ Q,
                                          const __bf16* __restrict__ Kb,
                                          const __bf16* __restrict__ Vb,
                                          float* __restrict__ O,
                                          float* __restrict__ num_ws,
                                          float* __restrict__ l_ws,
                                          __bf16* KtB, __bf16* VtB) {
  const int tid = threadIdx.x;
  const int lane = tid & 63;
  const int wave = tid >> 6;
  const int q32 = lane & 31;
  const int h32 = lane >> 5;

  // XCD-pinned decode (task%8 == xcd; matches prep's pinning).
  const int xcd = task & 7;
  const int idx = task >> 3;
  const int bs = 16 * splits;          // tasks per (b,h) pair
  const int pairl = idx / bs;          // 0..3
  const int sub = idx - pairl * bs;    // qb(4) | split
  const int pair = xcd * 4 + pairl;    // (b*8+h)
  const int qb = sub & 15;             // 16 q-blocks of 128 rows
  const int split = sub >> 4;
  const int h = pair & 7;
  const int b = pair >> 3;

  const int NT2 = (S_ / 32) / splits / 2;  // 64-s iterations
  const int tile0 = split * NT2 * 2;

  // ---- Q fragments for ONE 32-q group (B-operand: n=q32, k=h32*8+j)
  const float qscale = 0.125f * 1.44269504088896340736f;
  const int qrow = qb * 128 + wave * 32 + q32;
  bf16x8 qf[4];
  {
    const float* qp = Q + ((size_t)(b * L_ + qrow) * H_ + h) * 64;
#pragma unroll
    for (int c = 0; c < 4; ++c) {
      const float* p = qp + c * 16 + h32 * 8;
      float4 a = *(const float4*)p;
      float4 bb = *(const float4*)(p + 4);
      float t[8] = {a.x, a.y, a.z, a.w, bb.x, bb.y, bb.z, bb.w};
#pragma unroll
      for (int j = 0; j < 8; ++j) qf[c][j] = (__bf16)(t[j] * qscale);
    }
  }

  // ---- per-lane swizzled fragment offsets within a 4KB tile (R6 format)
  int koff[4];
#pragma unroll
  for (int c = 0; c < 4; ++c) koff[c] = (q32 * 8 + (((2 * c + h32) ^ (q32 & 7)))) * 8;
  int voff[2][2];
#pragma unroll
  for (int s2 = 0; s2 < 2; ++s2)
#pragma unroll
    for (int dt = 0; dt < 2; ++dt) {
      int dp = dt * 32 + q32;
      int Ll = dp >> 1;
      int ci = (dp & 1) * 4 + 2 * s2 + h32;
      voff[s2][dt] = (Ll * 8 + (ci ^ (Ll & 7))) * 8;
    }

  float l = 0.f;
  floatx16 ot[2];  // [d-tile]
#pragma unroll
  for (int r = 0; r < 16; ++r) { ot[0][r] = 0.f; ot[1][r] = 0.f; }

  const __bf16* KbBH = Kb + (size_t)(pair * 64) * TILE_ELEMS;
  const __bf16* VbBH = Vb + (size_t)(pair * 64) * TILE_ELEMS;
  const int lin8 = (wave * 64 + lane) * 8;

  // ---- prologue: async-stage tiles (tile0, tile0+1) into buf0
#pragma unroll
  for (int st = 0; st < 2; ++st) {
    async_load16(KbBH + (size_t)(tile0 + st) * TILE_ELEMS + lin8,
                 KtB + st * TILE_ELEMS + wave * 512);
    async_load16(VbBH + (size_t)(tile0 + st) * TILE_ELEMS + lin8,
                 VtB + st * TILE_ELEMS + wave * 512);
  }

  for (int t = 0; t < NT2; ++t) {
    const int buf = t & 1;
    __syncthreads();  // buf staged; all reads of buf^1 complete

    if (t + 1 < NT2) {
#pragma unroll
      for (int st = 0; st < 2; ++st) {
        async_load16(KbBH + (size_t)(tile0 + 2 * (t + 1) + st) * TILE_ELEMS + lin8,
                     KtB + (buf ^ 1) * (2 * TILE_ELEMS) + st * TILE_ELEMS + wave * 512);
        async_load16(VbBH + (size_t)(tile0 + 2 * (t + 1) + st) * TILE_ELEMS + lin8,
                     VtB + (buf ^ 1) * (2 * TILE_ELEMS) + st * TILE_ELEMS + wave * 512);
      }
    }

#pragma unroll
    for (int sb = 0; sb < 2; ++sb) {
      const __bf16* Kbuf = KtB + buf * (2 * TILE_ELEMS) + sb * TILE_ELEMS;
      const __bf16* Vbuf = VtB + buf * (2 * TILE_ELEMS) + sb * TILE_ELEMS;

      bf16x8 kA[4];
#pragma unroll
      for (int c = 0; c < 4; ++c) kA[c] = *(const bf16x8*)&Kbuf[koff[c]];

      floatx16 sc;
#pragma unroll
      for (int r = 0; r < 16; ++r) sc[r] = 0.f;
      __builtin_amdgcn_s_setprio(1);
#pragma unroll
      for (int c = 0; c < 4; ++c)
        sc = __builtin_amdgcn_mfma_f32_32x32x16_bf16(kA[c], qf[c], sc, 0, 0, 0);
      __builtin_amdgcn_s_setprio(0);

      bf16x8 p0, p1;
      softmax_pb(sc, h32, l, p0, p1);

      bf16x8 vA[4];  // [s2*2 + dt]
      vA[0] = *(const bf16x8*)&Vbuf[voff[0][0]];
      vA[1] = *(const bf16x8*)&Vbuf[voff[0][1]];
      vA[2] = *(const bf16x8*)&Vbuf[voff[1][0]];
      vA[3] = *(const bf16x8*)&Vbuf[voff[1][1]];
      __builtin_amdgcn_s_setprio(1);
      ot[0] = __builtin_amdgcn_mfma_f32_32x32x16_bf16(vA[0], p0, ot[0], 0, 0, 0);
      ot[1] = __builtin_amdgcn_mfma_f32_32x32x16_bf16(vA[1], p0, ot[1], 0, 0, 0);
      ot[0] = __builtin_amdgcn_mfma_f32_32x32x16_bf16(vA[2], p1, ot[0], 0, 0, 0);
      ot[1] = __builtin_amdgcn_mfma_f32_32x32x16_bf16(vA[3], p1, ot[1], 0, 0, 0);
      __builtin_amdgcn_s_setprio(0);
    }
  }

  // ---- epilogue
  {
    float lg = l + __shfl_xor(l, 32);
    if (splits == 1) {
      const float inv = 1.0f / lg;
      float* orow = O + ((size_t)(b * L_ + qrow) * H_ + h) * 64;
#pragma unroll
      for (int dt = 0; dt < 2; ++dt)
#pragma unroll
        for (int gg = 0; gg < 4; ++gg) {
          float4 v = {ot[dt][4 * gg + 0] * inv, ot[dt][4 * gg + 1] * inv,
                      ot[dt][4 * gg + 2] * inv, ot[dt][4 * gg + 3] * inv};
          *(float4*)(orow + dt * 32 + gg * 8 + h32 * 4) = v;
        }
    } else {
      float* nrow =
          num_ws + (size_t)split * NUMSZ + ((size_t)(b * L_ + qrow) * H_ + h) * 64;
#pragma unroll
      for (int dt = 0; dt < 2; ++dt)
#pragma unroll
        for (int gg = 0; gg < 4; ++gg) {
          float4 v = {ot[dt][4 * gg + 0], ot[dt][4 * gg + 1],
                      ot[dt][4 * gg + 2], ot[dt][4 * gg + 3]};
          *(float4*)(nrow + dt * 32 + gg * 8 + h32 * 4) = v;
        }
      if (h32 == 0)
        l_ws[(size_t)split * LSZ + (size_t)(b * L_ + qrow) * H_ + h] = lg;
    }
  }
}

// ============ R15 fused cooperative kernel: prep -> grid.sync -> attn ============
// grid MUST be 512 (2 blocks/CU co-resident: 32KB LDS, (256,2)). splits=1: no
// num_ws, no combine. Task strides are multiples of 8 -> XCD pinning preserved.
__global__ __launch_bounds__(256, 2) void fused_kernel(
    const float* __restrict__ Q, const float* __restrict__ K,
    const float* __restrict__ V, __bf16* __restrict__ Kb,
    __bf16* __restrict__ Vb, float* __restrict__ O) {
  __shared__ __align__(16) __bf16 Kt[2][2 * TILE_ELEMS];
  __shared__ __align__(16) __bf16 Vt[2][2 * TILE_ELEMS];
  const int bid = blockIdx.x;

  // phase 1: prep (2048 tile-tasks over 512 blocks = 4 each)
  for (int task = bid; task < B_ * H_ * 64; task += 512)
    prep_task(task, K, V, Kb, Vb, (float*)&Kt[0][0]);

  __threadfence();          // Kb/Vb visible device-wide
  cg::this_grid().sync();   // all prep done before any attn reads

  // phase 2: attn, splits=1 -> exactly 512 tasks, one per block
  attn_task(bid, 1, Q, Kb, Vb, O, nullptr, nullptr, &Kt[0][0], &Vt[0][0]);
}

// ============ fallback path (R14, proven 152us) ============
__global__ __launch_bounds__(256) void prep_kernel(const float* __restrict__ K,
                                                   const float* __restrict__ V,
                                                   __bf16* __restrict__ Kb,
                                                   __bf16* __restrict__ Vb) {
  __shared__ float Vs[32 * 64];
  prep_task(blockIdx.x, K, V, Kb, Vb, Vs);
}

__global__ __launch_bounds__(256, 3) void attn_kernel(const float* __restrict__ Q,
                                                      const __bf16* __restrict__ Kb,
                                                      const __bf16* __restrict__ Vb,
                                                      float* __restrict__ O,
                                                      float* __restrict__ num_ws,
                                                      float* __restrict__ l_ws,
                                                      int splits) {
  __shared__ __align__(16) __bf16 Kt[2][2 * TILE_ELEMS];
  __shared__ __align__(16) __bf16 Vt[2][2 * TILE_ELEMS];
  attn_task(blockIdx.x, splits, Q, Kb, Vb, O, num_ws, l_ws, &Kt[0][0], &Vt[0][0]);
}

__global__ __launch_bounds__(256) void combine_kernel(const float* __restrict__ num_ws,
                                                      const float* __restrict__ l_ws,
                                                      float* __restrict__ O, int splits) {
  const size_t i4 = ((size_t)blockIdx.x * 256 + threadIdx.x) * 4;
  float4 acc = {0.f, 0.f, 0.f, 0.f};
  float lt = 0.f;
  for (int s = 0; s < splits; ++s) {  // fixed order -> deterministic
    float4 v = *(const float4*)(num_ws + (size_t)s * NUMSZ + i4);
    acc.x += v.x; acc.y += v.y; acc.z += v.z; acc.w += v.w;
    lt += l_ws[(size_t)s * LSZ + (i4 >> 6)];
  }
  const float inv = 1.0f / lt;
  float4 o = {acc.x * inv, acc.y * inv, acc.z * inv, acc.w * inv};
  *(float4*)(O + i4) = o;
}

extern "C" void kernel_launch(void* const* d_in, const int* in_sizes, int n_in,
                              void* d_out, int out_size, void* d_ws, size_t ws_size,
                              hipStream_t stream) {
  const float* Q = (const float*)d_in[0];
  const float* K = (const float*)d_in[1];
  const float* V = (const float*)d_in[2];
  float* O = (float*)d_out;

  __bf16* Kb = (__bf16*)d_ws;
  __bf16* Vb = Kb + KVELEM;

  // ---- try the fused cooperative path (needs only Kb/Vb workspace)
  {
    void* args[6];
    args[0] = (void*)&Q;
    args[1] = (void*)&K;
    args[2] = (void*)&V;
    args[3] = (void*)&Kb;
    args[4] = (void*)&Vb;
    args[5] = (void*)&O;
    hipError_t e = hipLaunchCooperativeKernel((const void*)fused_kernel, dim3(512),
                                              dim3(256), (void**)args, 0, stream);
    if (e == hipSuccess) return;
    (void)hipGetLastError();  // clear; fall through to 3-kernel path
  }

  // ---- fallback: R14 3-kernel path
  float* num_ws = (float*)(Vb + KVELEM);
  const size_t base = (size_t)2 * KVELEM * sizeof(__bf16);
  const size_t per_split = ((size_t)NUMSZ + (size_t)LSZ) * sizeof(float);
  int splits = 1;
  if (ws_size >= base + 4 * per_split) splits = 4;
  else if (ws_size >= base + 2 * per_split) splits = 2;
  float* l_ws = num_ws + (size_t)splits * NUMSZ;

  prep_kernel<<<B_ * H_ * 64, 256, 0, stream>>>(K, V, Kb, Vb);
  dim3 grid(B_ * H_ * (L_ / 128) * splits);
  attn_kernel<<<grid, 256, 0, stream>>>(Q, Kb, Vb, O, num_ws, l_ws, splits);
  if (splits > 1) {
    combine_kernel<<<NUMSZ / 4 / 256, 256, 0, stream>>>(num_ws, l_ws, O, splits);
  }
}

// Round 7
// 148.023 us; speedup vs baseline: 1.5940x; 1.5940x over previous
//
#include <hip/hip_runtime.h>

// FullAttention: O[b,l,h,d] = softmax_s( scale * Q[b,l,h,:]·K[b,s,h,:] ) @ V[b,s,h,:]
// B=4, L=S=2048, H=8, E=D=64, fp32 in/out, bf16 MFMA compute.
// R16: R15 falsified the inter-kernel-overhead theory (fused coop kernel: 151us
//      single dispatch, total 236 -> the ~62us gap is harness-fixed reset cost;
//      cooperative path abandoned, it also serialized the 32q wave at 2 blk/CU).
//      Decomposition now: overhead~62 + prep~8 + combine(4)~17 + attn 59.4.
//      This round attacks attn + combine:
//      (1) dual-subtile ILP: process the two 32-s subtiles as independent chains
//          (QK0 -> QK1 -> SM0 -> PV0 -> SM1 -> PV1): softmax VALU hides under the
//          other chain's MFMAs (recovers R9's intra-wave overlap that the 32q
//          restructure lost). Staggered kA0/kA1 lifetimes keep peak ~150 regs
//          within the proven spill-free (256,3) budget.
//      (2) splits=3 UNEVEN (22/22/20 tiles): grid 1536 = 6 blocks/CU at 3-resident
//          = two exact phases, ZERO tail (splits=4 wasted ~12% in a 3,3,2 tail).
//          Combine traffic 84->68 MB.
//      Keep: XCD-pinned decode (FETCH 16.4 MB, KV L2-resident), async dbuf
//      staging, s_setprio on MFMA clusters.
//      Tripwires: attn WRITE ~51 MB (>70 = spill); attn >=59us = ILP null.

#define B_ 4
#define L_ 2048
#define S_ 2048
#define H_ 8

#define NUMSZ (B_ * L_ * H_ * 64)   // 4194304 floats
#define LSZ (B_ * L_ * H_)          // 65536 floats
#define KVELEM (B_ * H_ * S_ * 64)  // 4194304 bf16 per buffer
#define TILE_ELEMS 2048             // one 32-s tile = 4 KB

typedef __attribute__((ext_vector_type(8))) __bf16 bf16x8;
typedef __attribute__((ext_vector_type(4))) __bf16 bf16x4;
typedef __attribute__((ext_vector_type(16))) float floatx16;

union BF4U { bf16x4 v; uint2 u; };
union BF8U { bf16x8 v; uint4 u; };

__device__ __forceinline__ void async_load16(const void* g, void* l) {
  __builtin_amdgcn_global_load_lds(
      (const __attribute__((address_space(1))) unsigned int*)g,
      (__attribute__((address_space(3))) unsigned int*)l, 16, 0, 0);
}

__device__ __forceinline__ bf16x8 cvt8(float4 a, float4 b) {
  bf16x8 r;
  r[0] = (__bf16)a.x; r[1] = (__bf16)a.y; r[2] = (__bf16)a.z; r[3] = (__bf16)a.w;
  r[4] = (__bf16)b.x; r[5] = (__bf16)b.y; r[6] = (__bf16)b.z; r[7] = (__bf16)b.w;
  return r;
}

// max-free softmax on one 32x32 score block + in-register C->B transform
// (validated R5-R7). Outputs the two PV B-fragments (s-chunks 0,1).
__device__ __forceinline__ void softmax_pb(const floatx16& sc, int h32, float& l,
                                           bf16x8& pB0v, bf16x8& pB1v) {
  BF4U pg[4];
#pragma unroll
  for (int g = 0; g < 4; ++g) {
    float p0 = __builtin_amdgcn_exp2f(sc[4 * g + 0]);
    float p1 = __builtin_amdgcn_exp2f(sc[4 * g + 1]);
    float p2 = __builtin_amdgcn_exp2f(sc[4 * g + 2]);
    float p3 = __builtin_amdgcn_exp2f(sc[4 * g + 3]);
    l += (p0 + p1) + (p2 + p3);
    pg[g].v = (bf16x4){(__bf16)p0, (__bf16)p1, (__bf16)p2, (__bf16)p3};
  }
  uint2 sendA = h32 ? pg[0].u : pg[1].u;
  uint2 sendB = h32 ? pg[2].u : pg[3].u;
  uint2 recvA, recvB;
  recvA.x = __shfl_xor((int)sendA.x, 32);
  recvA.y = __shfl_xor((int)sendA.y, 32);
  recvB.x = __shfl_xor((int)sendB.x, 32);
  recvB.y = __shfl_xor((int)sendB.y, 32);
  BF8U pB0, pB1;
  if (h32 == 0) {
    pB0.u = (uint4){pg[0].u.x, pg[0].u.y, recvA.x, recvA.y};
    pB1.u = (uint4){pg[2].u.x, pg[2].u.y, recvB.x, recvB.y};
  } else {
    pB0.u = (uint4){recvA.x, recvA.y, pg[1].u.x, pg[1].u.y};
    pB1.u = (uint4){recvB.x, recvB.y, pg[3].u.x, pg[3].u.y};
  }
  pB0v = pB0.v;
  pB1v = pB1.v;
}

// ---- pre-pass: K,V fp32 -> bf16 swizzled 4KB tiles.
// XCD-pinned block decode — xcd = bid&7 owns (b,h) pairs [4*xcd, 4*xcd+3],
// matching attn's decode, so prep's L2 writes are attn's L2 hits.
__global__ __launch_bounds__(256) void prep_kernel(const float* __restrict__ K,
                                                   const float* __restrict__ V,
                                                   __bf16* __restrict__ Kb,
                                                   __bf16* __restrict__ Vb) {
  __shared__ float Vs[32 * 64];
  const int bid = blockIdx.x;
  const int xcd = bid & 7;
  const int idx = bid >> 3;            // 0..255 per XCD
  const int pair = xcd * 4 + (idx >> 6);  // (b*8+h), 4 pairs per XCD
  const int tile = idx & 63;
  const int h = pair & 7;
  const int b = pair >> 3;
  const int obid = pair * 64 + tile;   // output tile index
  const int s0 = tile * 32;
  const int i = threadIdx.x;

  {
    const int s = i >> 3, cp = i & 7;
    const int e0 = 8 * (cp ^ (s & 7));
    const float* src = K + (((size_t)(b * S_ + s0 + s) * H_ + h) * 64 + e0);
    float4 a = *(const float4*)src;
    float4 bb = *(const float4*)(src + 4);
    *(bf16x8*)(Kb + (size_t)obid * TILE_ELEMS + i * 8) = cvt8(a, bb);
  }
  {
    const int s = i >> 3, d0 = (i & 7) * 8;
    const float* src = V + (((size_t)(b * S_ + s0 + s) * H_ + h) * 64 + d0);
    float4 a = *(const float4*)src;
    float4 bb = *(const float4*)(src + 4);
    *(float4*)&Vs[s * 64 + d0] = a;
    *(float4*)&Vs[s * 64 + d0 + 4] = bb;
  }
  __syncthreads();
  {
    const int Ll = i >> 3, cp = i & 7;
    const int ci = cp ^ (Ll & 7);
    const int d = 2 * Ll + (ci >> 2);
    const int ch = ci & 3;
    BF8U o;
#pragma unroll
    for (int j = 0; j < 8; ++j) o.v[j] = (__bf16)Vs[(8 * ch + j) * 64 + d];
    *(bf16x8*)(Vb + (size_t)obid * TILE_ELEMS + i * 8) = o.v;
  }
}

__global__ __launch_bounds__(256, 3) void attn_kernel(const float* __restrict__ Q,
                                                      const __bf16* __restrict__ Kb,
                                                      const __bf16* __restrict__ Vb,
                                                      float* __restrict__ O,
                                                      float* __restrict__ num_ws,
                                                      float* __restrict__ l_ws,
                                                      int splits) {
  __shared__ __align__(16) __bf16 Kt[2][2 * TILE_ELEMS];  // dbuf, two 32-s sub-tiles
  __shared__ __align__(16) __bf16 Vt[2][2 * TILE_ELEMS];

  const int tid = threadIdx.x;
  const int lane = tid & 63;
  const int wave = tid >> 6;
  const int q32 = lane & 31;
  const int h32 = lane >> 5;

  // ---- XCD-pinned decode: xcd = bid&7; each XCD owns 4 (b,h) pairs.
  const int bid = blockIdx.x;
  const int xcd = bid & 7;
  const int idx = bid >> 3;
  const int bs = 16 * splits;          // tasks per (b,h) pair
  const int pairl = idx / bs;          // 0..3
  const int sub = idx - pairl * bs;    // qb(4) | split
  const int pair = xcd * 4 + pairl;    // (b*8+h)
  const int qb = sub & 15;             // 16 q-blocks of 128 rows
  const int split = sub >> 4;
  const int h = pair & 7;
  const int b = pair >> 3;

  // ---- S-range for this split. splits==3 is UNEVEN: 22/22/20 tiles.
  int nt2, tile0;
  if (splits == 3) {
    nt2 = (split < 2) ? 11 : 10;       // 64-s iterations
    tile0 = 22 * split;
  } else {
    nt2 = (S_ / 32) / (2 * splits);
    tile0 = split * 2 * nt2;
  }

  // ---- Q fragments for ONE 32-q group (B-operand: n=q32, k=h32*8+j)
  const float qscale = 0.125f * 1.44269504088896340736f;
  const int qrow = qb * 128 + wave * 32 + q32;
  bf16x8 qf[4];
  {
    const float* qp = Q + ((size_t)(b * L_ + qrow) * H_ + h) * 64;
#pragma unroll
    for (int c = 0; c < 4; ++c) {
      const float* p = qp + c * 16 + h32 * 8;
      float4 a = *(const float4*)p;
      float4 bb = *(const float4*)(p + 4);
      float t[8] = {a.x, a.y, a.z, a.w, bb.x, bb.y, bb.z, bb.w};
#pragma unroll
      for (int j = 0; j < 8; ++j) qf[c][j] = (__bf16)(t[j] * qscale);
    }
  }

  // ---- per-lane swizzled fragment offsets within a 4KB tile (R6 format)
  int koff[4];
#pragma unroll
  for (int c = 0; c < 4; ++c) koff[c] = (q32 * 8 + (((2 * c + h32) ^ (q32 & 7)))) * 8;
  int voff[2][2];
#pragma unroll
  for (int s2 = 0; s2 < 2; ++s2)
#pragma unroll
    for (int dt = 0; dt < 2; ++dt) {
      int dp = dt * 32 + q32;
      int Ll = dp >> 1;
      int ci = (dp & 1) * 4 + 2 * s2 + h32;
      voff[s2][dt] = (Ll * 8 + (ci ^ (Ll & 7))) * 8;
    }

  float l = 0.f;
  floatx16 ot[2];  // [d-tile]
#pragma unroll
  for (int r = 0; r < 16; ++r) { ot[0][r] = 0.f; ot[1][r] = 0.f; }

  const __bf16* KbBH = Kb + (size_t)(pair * 64) * TILE_ELEMS;
  const __bf16* VbBH = Vb + (size_t)(pair * 64) * TILE_ELEMS;
  const int lin8 = (wave * 64 + lane) * 8;

  // ---- prologue: async-stage tiles (tile0, tile0+1) into buf0
#pragma unroll
  for (int st = 0; st < 2; ++st) {
    async_load16(KbBH + (size_t)(tile0 + st) * TILE_ELEMS + lin8,
                 &Kt[0][st * TILE_ELEMS + wave * 512]);
    async_load16(VbBH + (size_t)(tile0 + st) * TILE_ELEMS + lin8,
                 &Vt[0][st * TILE_ELEMS + wave * 512]);
  }

  for (int t = 0; t < nt2; ++t) {
    const int buf = t & 1;
    __syncthreads();  // buf staged; all reads of buf^1 complete

    if (t + 1 < nt2) {
#pragma unroll
      for (int st = 0; st < 2; ++st) {
        async_load16(KbBH + (size_t)(tile0 + 2 * (t + 1) + st) * TILE_ELEMS + lin8,
                     &Kt[buf ^ 1][st * TILE_ELEMS + wave * 512]);
        async_load16(VbBH + (size_t)(tile0 + 2 * (t + 1) + st) * TILE_ELEMS + lin8,
                     &Vt[buf ^ 1][st * TILE_ELEMS + wave * 512]);
      }
    }

    // ---- R16 dual-subtile ILP: two independent chains (sc0 / sc1); each
    // softmax's VALU hides under the other chain's MFMAs.
    const __bf16* Kbuf0 = &Kt[buf][0];
    const __bf16* Kbuf1 = &Kt[buf][TILE_ELEMS];
    const __bf16* Vbuf0 = &Vt[buf][0];
    const __bf16* Vbuf1 = &Vt[buf][TILE_ELEMS];

    // QK chain 0
    floatx16 sc0;
#pragma unroll
    for (int r = 0; r < 16; ++r) sc0[r] = 0.f;
    {
      bf16x8 kA0[4];
#pragma unroll
      for (int c = 0; c < 4; ++c) kA0[c] = *(const bf16x8*)&Kbuf0[koff[c]];
      __builtin_amdgcn_s_setprio(1);
#pragma unroll
      for (int c = 0; c < 4; ++c)
        sc0 = __builtin_amdgcn_mfma_f32_32x32x16_bf16(kA0[c], qf[c], sc0, 0, 0, 0);
      __builtin_amdgcn_s_setprio(0);
    }
    // QK chain 1 (independent; fills the pipe while chain 0 completes)
    floatx16 sc1;
#pragma unroll
    for (int r = 0; r < 16; ++r) sc1[r] = 0.f;
    {
      bf16x8 kA1[4];
#pragma unroll
      for (int c = 0; c < 4; ++c) kA1[c] = *(const bf16x8*)&Kbuf1[koff[c]];
      __builtin_amdgcn_s_setprio(1);
#pragma unroll
      for (int c = 0; c < 4; ++c)
        sc1 = __builtin_amdgcn_mfma_f32_32x32x16_bf16(kA1[c], qf[c], sc1, 0, 0, 0);
      __builtin_amdgcn_s_setprio(0);
    }

    // softmax 0 overlaps QK1's MFMA execution
    bf16x8 p00, p01;
    softmax_pb(sc0, h32, l, p00, p01);

    // PV subtile 0
    {
      bf16x8 vA0[4];
      vA0[0] = *(const bf16x8*)&Vbuf0[voff[0][0]];
      vA0[1] = *(const bf16x8*)&Vbuf0[voff[0][1]];
      vA0[2] = *(const bf16x8*)&Vbuf0[voff[1][0]];
      vA0[3] = *(const bf16x8*)&Vbuf0[voff[1][1]];
      __builtin_amdgcn_s_setprio(1);
      ot[0] = __builtin_amdgcn_mfma_f32_32x32x16_bf16(vA0[0], p00, ot[0], 0, 0, 0);
      ot[1] = __builtin_amdgcn_mfma_f32_32x32x16_bf16(vA0[1], p00, ot[1], 0, 0, 0);
      ot[0] = __builtin_amdgcn_mfma_f32_32x32x16_bf16(vA0[2], p01, ot[0], 0, 0, 0);
      ot[1] = __builtin_amdgcn_mfma_f32_32x32x16_bf16(vA0[3], p01, ot[1], 0, 0, 0);
      __builtin_amdgcn_s_setprio(0);
    }

    // softmax 1 overlaps PV0's MFMA execution
    bf16x8 p10, p11;
    softmax_pb(sc1, h32, l, p10, p11);

    // PV subtile 1
    {
      bf16x8 vA1[4];
      vA1[0] = *(const bf16x8*)&Vbuf1[voff[0][0]];
      vA1[1] = *(const bf16x8*)&Vbuf1[voff[0][1]];
      vA1[2] = *(const bf16x8*)&Vbuf1[voff[1][0]];
      vA1[3] = *(const bf16x8*)&Vbuf1[voff[1][1]];
      __builtin_amdgcn_s_setprio(1);
      ot[0] = __builtin_amdgcn_mfma_f32_32x32x16_bf16(vA1[0], p10, ot[0], 0, 0, 0);
      ot[1] = __builtin_amdgcn_mfma_f32_32x32x16_bf16(vA1[1], p10, ot[1], 0, 0, 0);
      ot[0] = __builtin_amdgcn_mfma_f32_32x32x16_bf16(vA1[2], p11, ot[0], 0, 0, 0);
      ot[1] = __builtin_amdgcn_mfma_f32_32x32x16_bf16(vA1[3], p11, ot[1], 0, 0, 0);
      __builtin_amdgcn_s_setprio(0);
    }
  }

  // ---- epilogue
  {
    float lg = l + __shfl_xor(l, 32);
    if (splits == 1) {
      const float inv = 1.0f / lg;
      float* orow = O + ((size_t)(b * L_ + qrow) * H_ + h) * 64;
#pragma unroll
      for (int dt = 0; dt < 2; ++dt)
#pragma unroll
        for (int gg = 0; gg < 4; ++gg) {
          float4 v = {ot[dt][4 * gg + 0] * inv, ot[dt][4 * gg + 1] * inv,
                      ot[dt][4 * gg + 2] * inv, ot[dt][4 * gg + 3] * inv};
          *(float4*)(orow + dt * 32 + gg * 8 + h32 * 4) = v;
        }
    } else {
      float* nrow =
          num_ws + (size_t)split * NUMSZ + ((size_t)(b * L_ + qrow) * H_ + h) * 64;
#pragma unroll
      for (int dt = 0; dt < 2; ++dt)
#pragma unroll
        for (int gg = 0; gg < 4; ++gg) {
          float4 v = {ot[dt][4 * gg + 0], ot[dt][4 * gg + 1],
                      ot[dt][4 * gg + 2], ot[dt][4 * gg + 3]};
          *(float4*)(nrow + dt * 32 + gg * 8 + h32 * 4) = v;
        }
      if (h32 == 0)
        l_ws[(size_t)split * LSZ + (size_t)(b * L_ + qrow) * H_ + h] = lg;
    }
  }
}

__global__ __launch_bounds__(256) void combine_kernel(const float* __restrict__ num_ws,
                                                      const float* __restrict__ l_ws,
                                                      float* __restrict__ O, int splits) {
  const size_t i4 = ((size_t)blockIdx.x * 256 + threadIdx.x) * 4;
  float4 acc = {0.f, 0.f, 0.f, 0.f};
  float lt = 0.f;
  for (int s = 0; s < splits; ++s) {  // fixed order -> deterministic
    float4 v = *(const float4*)(num_ws + (size_t)s * NUMSZ + i4);
    acc.x += v.x; acc.y += v.y; acc.z += v.z; acc.w += v.w;
    lt += l_ws[(size_t)s * LSZ + (i4 >> 6)];
  }
  const float inv = 1.0f / lt;
  float4 o = {acc.x * inv, acc.y * inv, acc.z * inv, acc.w * inv};
  *(float4*)(O + i4) = o;
}

extern "C" void kernel_launch(void* const* d_in, const int* in_sizes, int n_in,
                              void* d_out, int out_size, void* d_ws, size_t ws_size,
                              hipStream_t stream) {
  const float* Q = (const float*)d_in[0];
  const float* K = (const float*)d_in[1];
  const float* V = (const float*)d_in[2];
  float* O = (float*)d_out;

  __bf16* Kb = (__bf16*)d_ws;
  __bf16* Vb = Kb + KVELEM;
  float* num_ws = (float*)(Vb + KVELEM);
  const size_t base = (size_t)2 * KVELEM * sizeof(__bf16);
  const size_t per_split = ((size_t)NUMSZ + (size_t)LSZ) * sizeof(float);
  int splits = 1;
  if (ws_size >= base + 3 * per_split) splits = 3;        // 1536 blocks, zero tail
  else if (ws_size >= base + 2 * per_split) splits = 2;   // 1024 blocks
  float* l_ws = num_ws + (size_t)splits * NUMSZ;

  prep_kernel<<<B_ * H_ * 64, 256, 0, stream>>>(K, V, Kb, Vb);
  dim3 grid(B_ * H_ * 16 * splits);
  attn_kernel<<<grid, 256, 0, stream>>>(Q, Kb, Vb, O, num_ws, l_ws, splits);
  if (splits > 1) {
    combine_kernel<<<NUMSZ / 4 / 256, 256, 0, stream>>>(num_ws, l_ws, O, splits);
  }
}

// Round 8
// 147.277 us; speedup vs baseline: 1.6021x; 1.0051x over previous
//
#include <hip/hip_runtime.h>

// FullAttention: O[b,l,h,d] = softmax_s( scale * Q[b,l,h,:]·K[b,s,h,:] ) @ V[b,s,h,:]
// B=4, L=S=2048, H=8, E=D=64, fp32 in/out, bf16 MFMA compute.
// R17: R16's ILP reorder + splits=3 were NULL -> attn pinned at 59.5us across
//      occupancy 17-33%: the classic 2-phase stall (every iteration ends in
//      __syncthreads whose implicit s_waitcnt vmcnt(0) drains the staging queue
//      while ALL waves block; ~45% idle cycles). This round ports the T3/T4
//      counted-vmcnt schedule: THREE LDS buffers (48KB, 3 blocks/CU = 144KB ok),
//      stage issued 2 iterations ahead (8 loads in flight), per-iter sync =
//      asm s_waitcnt vmcnt(4) + raw s_barrier (never drain to 0 in the loop;
//      vmcnt(0) only on the last iteration). One barrier/iter is sufficient:
//      buffer (t+2)%3 staged at iter t was last read at t-1 which precedes
//      barrier t in every wave. Loop body has no other VMEM ops -> vmcnt
//      arithmetic exact. Compute body = R16 verbatim (delta attributable).
//      Keep: splits=3 uneven, XCD pinning, (256,3), setprio.
//      Tripwires: passed=false -> race, revert; dur ~59 + MfmaUtil flat ->
//      stall is load latency, go deeper prefetch; WRITE >70MB -> spill.

#define B_ 4
#define L_ 2048
#define S_ 2048
#define H_ 8

#define NUMSZ (B_ * L_ * H_ * 64)   // 4194304 floats
#define LSZ (B_ * L_ * H_)          // 65536 floats
#define KVELEM (B_ * H_ * S_ * 64)  // 4194304 bf16 per buffer
#define TILE_ELEMS 2048             // one 32-s tile = 4 KB

typedef __attribute__((ext_vector_type(8))) __bf16 bf16x8;
typedef __attribute__((ext_vector_type(4))) __bf16 bf16x4;
typedef __attribute__((ext_vector_type(16))) float floatx16;

union BF4U { bf16x4 v; uint2 u; };
union BF8U { bf16x8 v; uint4 u; };

__device__ __forceinline__ void async_load16(const void* g, void* l) {
  __builtin_amdgcn_global_load_lds(
      (const __attribute__((address_space(1))) unsigned int*)g,
      (__attribute__((address_space(3))) unsigned int*)l, 16, 0, 0);
}

__device__ __forceinline__ bf16x8 cvt8(float4 a, float4 b) {
  bf16x8 r;
  r[0] = (__bf16)a.x; r[1] = (__bf16)a.y; r[2] = (__bf16)a.z; r[3] = (__bf16)a.w;
  r[4] = (__bf16)b.x; r[5] = (__bf16)b.y; r[6] = (__bf16)b.z; r[7] = (__bf16)b.w;
  return r;
}

// max-free softmax on one 32x32 score block + in-register C->B transform
// (validated R5-R7). Outputs the two PV B-fragments (s-chunks 0,1).
__device__ __forceinline__ void softmax_pb(const floatx16& sc, int h32, float& l,
                                           bf16x8& pB0v, bf16x8& pB1v) {
  BF4U pg[4];
#pragma unroll
  for (int g = 0; g < 4; ++g) {
    float p0 = __builtin_amdgcn_exp2f(sc[4 * g + 0]);
    float p1 = __builtin_amdgcn_exp2f(sc[4 * g + 1]);
    float p2 = __builtin_amdgcn_exp2f(sc[4 * g + 2]);
    float p3 = __builtin_amdgcn_exp2f(sc[4 * g + 3]);
    l += (p0 + p1) + (p2 + p3);
    pg[g].v = (bf16x4){(__bf16)p0, (__bf16)p1, (__bf16)p2, (__bf16)p3};
  }
  uint2 sendA = h32 ? pg[0].u : pg[1].u;
  uint2 sendB = h32 ? pg[2].u : pg[3].u;
  uint2 recvA, recvB;
  recvA.x = __shfl_xor((int)sendA.x, 32);
  recvA.y = __shfl_xor((int)sendA.y, 32);
  recvB.x = __shfl_xor((int)sendB.x, 32);
  recvB.y = __shfl_xor((int)sendB.y, 32);
  BF8U pB0, pB1;
  if (h32 == 0) {
    pB0.u = (uint4){pg[0].u.x, pg[0].u.y, recvA.x, recvA.y};
    pB1.u = (uint4){pg[2].u.x, pg[2].u.y, recvB.x, recvB.y};
  } else {
    pB0.u = (uint4){recvA.x, recvA.y, pg[1].u.x, pg[1].u.y};
    pB1.u = (uint4){recvB.x, recvB.y, pg[3].u.x, pg[3].u.y};
  }
  pB0v = pB0.v;
  pB1v = pB1.v;
}

// ---- pre-pass: K,V fp32 -> bf16 swizzled 4KB tiles.
// XCD-pinned block decode — xcd = bid&7 owns (b,h) pairs [4*xcd, 4*xcd+3].
__global__ __launch_bounds__(256) void prep_kernel(const float* __restrict__ K,
                                                   const float* __restrict__ V,
                                                   __bf16* __restrict__ Kb,
                                                   __bf16* __restrict__ Vb) {
  __shared__ float Vs[32 * 64];
  const int bid = blockIdx.x;
  const int xcd = bid & 7;
  const int idx = bid >> 3;            // 0..255 per XCD
  const int pair = xcd * 4 + (idx >> 6);  // (b*8+h), 4 pairs per XCD
  const int tile = idx & 63;
  const int h = pair & 7;
  const int b = pair >> 3;
  const int obid = pair * 64 + tile;   // output tile index
  const int s0 = tile * 32;
  const int i = threadIdx.x;

  {
    const int s = i >> 3, cp = i & 7;
    const int e0 = 8 * (cp ^ (s & 7));
    const float* src = K + (((size_t)(b * S_ + s0 + s) * H_ + h) * 64 + e0);
    float4 a = *(const float4*)src;
    float4 bb = *(const float4*)(src + 4);
    *(bf16x8*)(Kb + (size_t)obid * TILE_ELEMS + i * 8) = cvt8(a, bb);
  }
  {
    const int s = i >> 3, d0 = (i & 7) * 8;
    const float* src = V + (((size_t)(b * S_ + s0 + s) * H_ + h) * 64 + d0);
    float4 a = *(const float4*)src;
    float4 bb = *(const float4*)(src + 4);
    *(float4*)&Vs[s * 64 + d0] = a;
    *(float4*)&Vs[s * 64 + d0 + 4] = bb;
  }
  __syncthreads();
  {
    const int Ll = i >> 3, cp = i & 7;
    const int ci = cp ^ (Ll & 7);
    const int d = 2 * Ll + (ci >> 2);
    const int ch = ci & 3;
    BF8U o;
#pragma unroll
    for (int j = 0; j < 8; ++j) o.v[j] = (__bf16)Vs[(8 * ch + j) * 64 + d];
    *(bf16x8*)(Vb + (size_t)obid * TILE_ELEMS + i * 8) = o.v;
  }
}

__global__ __launch_bounds__(256, 3) void attn_kernel(const float* __restrict__ Q,
                                                      const __bf16* __restrict__ Kb,
                                                      const __bf16* __restrict__ Vb,
                                                      float* __restrict__ O,
                                                      float* __restrict__ num_ws,
                                                      float* __restrict__ l_ws,
                                                      int splits) {
  // R17: TRI-buffered staging (48 KB total; 3 blocks/CU = 144 KB <= 160 KB).
  __shared__ __align__(16) __bf16 Kt[3][2 * TILE_ELEMS];
  __shared__ __align__(16) __bf16 Vt[3][2 * TILE_ELEMS];

  const int tid = threadIdx.x;
  const int lane = tid & 63;
  const int wave = tid >> 6;
  const int q32 = lane & 31;
  const int h32 = lane >> 5;

  // ---- XCD-pinned decode: xcd = bid&7; each XCD owns 4 (b,h) pairs.
  const int bid = blockIdx.x;
  const int xcd = bid & 7;
  const int idx = bid >> 3;
  const int bs = 16 * splits;          // tasks per (b,h) pair
  const int pairl = idx / bs;          // 0..3
  const int sub = idx - pairl * bs;    // qb(4) | split
  const int pair = xcd * 4 + pairl;    // (b*8+h)
  const int qb = sub & 15;             // 16 q-blocks of 128 rows
  const int split = sub >> 4;
  const int h = pair & 7;
  const int b = pair >> 3;

  // ---- S-range for this split. splits==3 is UNEVEN: 22/22/20 tiles.
  int nt2, tile0;
  if (splits == 3) {
    nt2 = (split < 2) ? 11 : 10;       // 64-s iterations
    tile0 = 22 * split;
  } else {
    nt2 = (S_ / 32) / (2 * splits);
    tile0 = split * 2 * nt2;
  }

  // ---- Q fragments for ONE 32-q group (B-operand: n=q32, k=h32*8+j)
  const float qscale = 0.125f * 1.44269504088896340736f;
  const int qrow = qb * 128 + wave * 32 + q32;
  bf16x8 qf[4];
  {
    const float* qp = Q + ((size_t)(b * L_ + qrow) * H_ + h) * 64;
#pragma unroll
    for (int c = 0; c < 4; ++c) {
      const float* p = qp + c * 16 + h32 * 8;
      float4 a = *(const float4*)p;
      float4 bb = *(const float4*)(p + 4);
      float t[8] = {a.x, a.y, a.z, a.w, bb.x, bb.y, bb.z, bb.w};
#pragma unroll
      for (int j = 0; j < 8; ++j) qf[c][j] = (__bf16)(t[j] * qscale);
    }
  }

  // ---- per-lane swizzled fragment offsets within a 4KB tile (R6 format)
  int koff[4];
#pragma unroll
  for (int c = 0; c < 4; ++c) koff[c] = (q32 * 8 + (((2 * c + h32) ^ (q32 & 7)))) * 8;
  int voff[2][2];
#pragma unroll
  for (int s2 = 0; s2 < 2; ++s2)
#pragma unroll
    for (int dt = 0; dt < 2; ++dt) {
      int dp = dt * 32 + q32;
      int Ll = dp >> 1;
      int ci = (dp & 1) * 4 + 2 * s2 + h32;
      voff[s2][dt] = (Ll * 8 + (ci ^ (Ll & 7))) * 8;
    }

  float l = 0.f;
  floatx16 ot[2];  // [d-tile]
#pragma unroll
  for (int r = 0; r < 16; ++r) { ot[0][r] = 0.f; ot[1][r] = 0.f; }

  const __bf16* KbBH = Kb + (size_t)(pair * 64) * TILE_ELEMS;
  const __bf16* VbBH = Vb + (size_t)(pair * 64) * TILE_ELEMS;
  const int lin8 = (wave * 64 + lane) * 8;

  // stage one 64-s pair (tiles tp, tp+1) into buffer bufi: 4 vmcnt events/wave.
  auto stage = [&](int bufi, int tp) {
    async_load16(KbBH + (size_t)tp * TILE_ELEMS + lin8, &Kt[bufi][wave * 512]);
    async_load16(KbBH + (size_t)(tp + 1) * TILE_ELEMS + lin8,
                 &Kt[bufi][TILE_ELEMS + wave * 512]);
    async_load16(VbBH + (size_t)tp * TILE_ELEMS + lin8, &Vt[bufi][wave * 512]);
    async_load16(VbBH + (size_t)(tp + 1) * TILE_ELEMS + lin8,
                 &Vt[bufi][TILE_ELEMS + wave * 512]);
  };

  // ---- prologue: 2 batches in flight (8 loads/wave)
  stage(0, tile0);
  if (nt2 > 1) stage(1, tile0 + 2);

  int cur = 0;
  for (int t = 0; t < nt2; ++t) {
    // Counted wait: batch(t) is the oldest 4 of <=8 outstanding. Only the last
    // iteration drains fully. THEN raw barrier: all waves' batch(t) visible.
    if (t + 1 < nt2) {
      asm volatile("s_waitcnt vmcnt(4)" ::: "memory");
    } else {
      asm volatile("s_waitcnt vmcnt(0)" ::: "memory");
    }
    asm volatile("s_barrier" ::: "memory");

    // Refill: buffer (cur+2)%3 was last read at iter t-1, which precedes
    // barrier t in every wave -> overwrite-safe.
    if (t + 2 < nt2) {
      int nn = cur + 2; if (nn >= 3) nn -= 3;
      stage(nn, tile0 + 2 * (t + 2));
    }

    // ---- compute body (R16 verbatim) on buffer cur
    const __bf16* Kbuf0 = &Kt[cur][0];
    const __bf16* Kbuf1 = &Kt[cur][TILE_ELEMS];
    const __bf16* Vbuf0 = &Vt[cur][0];
    const __bf16* Vbuf1 = &Vt[cur][TILE_ELEMS];

    floatx16 sc0;
#pragma unroll
    for (int r = 0; r < 16; ++r) sc0[r] = 0.f;
    {
      bf16x8 kA0[4];
#pragma unroll
      for (int c = 0; c < 4; ++c) kA0[c] = *(const bf16x8*)&Kbuf0[koff[c]];
      __builtin_amdgcn_s_setprio(1);
#pragma unroll
      for (int c = 0; c < 4; ++c)
        sc0 = __builtin_amdgcn_mfma_f32_32x32x16_bf16(kA0[c], qf[c], sc0, 0, 0, 0);
      __builtin_amdgcn_s_setprio(0);
    }
    floatx16 sc1;
#pragma unroll
    for (int r = 0; r < 16; ++r) sc1[r] = 0.f;
    {
      bf16x8 kA1[4];
#pragma unroll
      for (int c = 0; c < 4; ++c) kA1[c] = *(const bf16x8*)&Kbuf1[koff[c]];
      __builtin_amdgcn_s_setprio(1);
#pragma unroll
      for (int c = 0; c < 4; ++c)
        sc1 = __builtin_amdgcn_mfma_f32_32x32x16_bf16(kA1[c], qf[c], sc1, 0, 0, 0);
      __builtin_amdgcn_s_setprio(0);
    }

    bf16x8 p00, p01;
    softmax_pb(sc0, h32, l, p00, p01);
    {
      bf16x8 vA0[4];
      vA0[0] = *(const bf16x8*)&Vbuf0[voff[0][0]];
      vA0[1] = *(const bf16x8*)&Vbuf0[voff[0][1]];
      vA0[2] = *(const bf16x8*)&Vbuf0[voff[1][0]];
      vA0[3] = *(const bf16x8*)&Vbuf0[voff[1][1]];
      __builtin_amdgcn_s_setprio(1);
      ot[0] = __builtin_amdgcn_mfma_f32_32x32x16_bf16(vA0[0], p00, ot[0], 0, 0, 0);
      ot[1] = __builtin_amdgcn_mfma_f32_32x32x16_bf16(vA0[1], p00, ot[1], 0, 0, 0);
      ot[0] = __builtin_amdgcn_mfma_f32_32x32x16_bf16(vA0[2], p01, ot[0], 0, 0, 0);
      ot[1] = __builtin_amdgcn_mfma_f32_32x32x16_bf16(vA0[3], p01, ot[1], 0, 0, 0);
      __builtin_amdgcn_s_setprio(0);
    }

    bf16x8 p10, p11;
    softmax_pb(sc1, h32, l, p10, p11);
    {
      bf16x8 vA1[4];
      vA1[0] = *(const bf16x8*)&Vbuf1[voff[0][0]];
      vA1[1] = *(const bf16x8*)&Vbuf1[voff[0][1]];
      vA1[2] = *(const bf16x8*)&Vbuf1[voff[1][0]];
      vA1[3] = *(const bf16x8*)&Vbuf1[voff[1][1]];
      __builtin_amdgcn_s_setprio(1);
      ot[0] = __builtin_amdgcn_mfma_f32_32x32x16_bf16(vA1[0], p10, ot[0], 0, 0, 0);
      ot[1] = __builtin_amdgcn_mfma_f32_32x32x16_bf16(vA1[1], p10, ot[1], 0, 0, 0);
      ot[0] = __builtin_amdgcn_mfma_f32_32x32x16_bf16(vA1[2], p11, ot[0], 0, 0, 0);
      ot[1] = __builtin_amdgcn_mfma_f32_32x32x16_bf16(vA1[3], p11, ot[1], 0, 0, 0);
      __builtin_amdgcn_s_setprio(0);
    }

    cur = (cur + 1 == 3) ? 0 : cur + 1;
  }

  // ---- epilogue
  {
    float lg = l + __shfl_xor(l, 32);
    if (splits == 1) {
      const float inv = 1.0f / lg;
      float* orow = O + ((size_t)(b * L_ + qrow) * H_ + h) * 64;
#pragma unroll
      for (int dt = 0; dt < 2; ++dt)
#pragma unroll
        for (int gg = 0; gg < 4; ++gg) {
          float4 v = {ot[dt][4 * gg + 0] * inv, ot[dt][4 * gg + 1] * inv,
                      ot[dt][4 * gg + 2] * inv, ot[dt][4 * gg + 3] * inv};
          *(float4*)(orow + dt * 32 + gg * 8 + h32 * 4) = v;
        }
    } else {
      float* nrow =
          num_ws + (size_t)split * NUMSZ + ((size_t)(b * L_ + qrow) * H_ + h) * 64;
#pragma unroll
      for (int dt = 0; dt < 2; ++dt)
#pragma unroll
        for (int gg = 0; gg < 4; ++gg) {
          float4 v = {ot[dt][4 * gg + 0], ot[dt][4 * gg + 1],
                      ot[dt][4 * gg + 2], ot[dt][4 * gg + 3]};
          *(float4*)(nrow + dt * 32 + gg * 8 + h32 * 4) = v;
        }
      if (h32 == 0)
        l_ws[(size_t)split * LSZ + (size_t)(b * L_ + qrow) * H_ + h] = lg;
    }
  }
}

__global__ __launch_bounds__(256) void combine_kernel(const float* __restrict__ num_ws,
                                                      const float* __restrict__ l_ws,
                                                      float* __restrict__ O, int splits) {
  const size_t i4 = ((size_t)blockIdx.x * 256 + threadIdx.x) * 4;
  float4 acc = {0.f, 0.f, 0.f, 0.f};
  float lt = 0.f;
  for (int s = 0; s < splits; ++s) {  // fixed order -> deterministic
    float4 v = *(const float4*)(num_ws + (size_t)s * NUMSZ + i4);
    acc.x += v.x; acc.y += v.y; acc.z += v.z; acc.w += v.w;
    lt += l_ws[(size_t)s * LSZ + (i4 >> 6)];
  }
  const float inv = 1.0f / lt;
  float4 o = {acc.x * inv, acc.y * inv, acc.z * inv, acc.w * inv};
  *(float4*)(O + i4) = o;
}

extern "C" void kernel_launch(void* const* d_in, const int* in_sizes, int n_in,
                              void* d_out, int out_size, void* d_ws, size_t ws_size,
                              hipStream_t stream) {
  const float* Q = (const float*)d_in[0];
  const float* K = (const float*)d_in[1];
  const float* V = (const float*)d_in[2];
  float* O = (float*)d_out;

  __bf16* Kb = (__bf16*)d_ws;
  __bf16* Vb = Kb + KVELEM;
  float* num_ws = (float*)(Vb + KVELEM);
  const size_t base = (size_t)2 * KVELEM * sizeof(__bf16);
  const size_t per_split = ((size_t)NUMSZ + (size_t)LSZ) * sizeof(float);
  int splits = 1;
  if (ws_size >= base + 3 * per_split) splits = 3;        // 1536 blocks, zero tail
  else if (ws_size >= base + 2 * per_split) splits = 2;   // 1024 blocks
  float* l_ws = num_ws + (size_t)splits * NUMSZ;

  prep_kernel<<<B_ * H_ * 64, 256, 0, stream>>>(K, V, Kb, Vb);
  dim3 grid(B_ * H_ * 16 * splits);
  attn_kernel<<<grid, 256, 0, stream>>>(Q, Kb, Vb, O, num_ws, l_ws, splits);
  if (splits > 1) {
    combine_kernel<<<NUMSZ / 4 / 256, 256, 0, stream>>>(num_ws, l_ws, O, splits);
  }
}

// Round 10
// 145.803 us; speedup vs baseline: 1.6183x; 1.0101x over previous
//
#include <hip/hip_runtime.h>

// FullAttention: O[b,l,h,d] = softmax_s( scale * Q[b,l,h,:]·K[b,s,h,:] ) @ V[b,s,h,:]
// B=4, L=S=2048, H=8, E=D=64, fp32 in/out, bf16 MFMA compute.
// R19 = R18 resubmitted verbatim (R18 bench died in infra: "container failed
//       twice", no data — same as R3/R13 precedent; resubmit to keep the delta
//       attributable).
// R18: five structural nulls (occupancy, ILP, tails, counted-vmcnt) prove attn is
//      not MFMA-(6% true demand), occupancy-, or barrier-bound. Remaining serial
//      cost: LDS machinery (16 ds_read_b128 + 4.2M bank-conflict cyc + staging +
//      barriers) guarding data that is ALREADY L2-RESIDENT (XCD pinning -> 2MB
//      KV per 4MB XCD-L2; FETCH=16MB proves it). Per m169 precedent (drop
//      staging when KV L2-fits: +26%), this round deletes the entire LDS path:
//      Kb/Vb re-laid out FRAGMENT-MAJOR (chunk c x lane) so every MFMA operand
//      is one coalesced 1KB global_load_dwordx4 from L2. No __shared__, no
//      barriers, no waitcnt choreography in attn; waves run free (3/SIMD,
//      (256,3)). splits=2 (combine 14->10us).
//      Predictions: attn 60.7 -> 42-50us; LDS_Block_Size=0; bank conflicts ~0;
//      FETCH ~16MB (ballooning = L2 thrash = pinning broke); WRITE ~36MB
//      (>60 = spill); total ~125-133us. dur>=58 => softmax critical path is the
//      plateau -> next lever is algorithmic.

#define B_ 4
#define L_ 2048
#define S_ 2048
#define H_ 8

#define NUMSZ (B_ * L_ * H_ * 64)   // 4194304 floats
#define LSZ (B_ * L_ * H_)          // 65536 floats
#define KVELEM (B_ * H_ * S_ * 64)  // 4194304 bf16 per buffer
#define TILE_ELEMS 2048             // one 32-s tile = 4 KB

typedef __attribute__((ext_vector_type(8))) __bf16 bf16x8;
typedef __attribute__((ext_vector_type(4))) __bf16 bf16x4;
typedef __attribute__((ext_vector_type(16))) float floatx16;

union BF4U { bf16x4 v; uint2 u; };
union BF8U { bf16x8 v; uint4 u; };

__device__ __forceinline__ bf16x8 cvt8(float4 a, float4 b) {
  bf16x8 r;
  r[0] = (__bf16)a.x; r[1] = (__bf16)a.y; r[2] = (__bf16)a.z; r[3] = (__bf16)a.w;
  r[4] = (__bf16)b.x; r[5] = (__bf16)b.y; r[6] = (__bf16)b.z; r[7] = (__bf16)b.w;
  return r;
}

// max-free softmax on one 32x32 score block + in-register C->B transform
// (validated R5-R7). Outputs the two PV B-fragments (s-chunks 0,1).
__device__ __forceinline__ void softmax_pb(const floatx16& sc, int h32, float& l,
                                           bf16x8& pB0v, bf16x8& pB1v) {
  BF4U pg[4];
#pragma unroll
  for (int g = 0; g < 4; ++g) {
    float p0 = __builtin_amdgcn_exp2f(sc[4 * g + 0]);
    float p1 = __builtin_amdgcn_exp2f(sc[4 * g + 1]);
    float p2 = __builtin_amdgcn_exp2f(sc[4 * g + 2]);
    float p3 = __builtin_amdgcn_exp2f(sc[4 * g + 3]);
    l += (p0 + p1) + (p2 + p3);
    pg[g].v = (bf16x4){(__bf16)p0, (__bf16)p1, (__bf16)p2, (__bf16)p3};
  }
  uint2 sendA = h32 ? pg[0].u : pg[1].u;
  uint2 sendB = h32 ? pg[2].u : pg[3].u;
  uint2 recvA, recvB;
  recvA.x = __shfl_xor((int)sendA.x, 32);
  recvA.y = __shfl_xor((int)sendA.y, 32);
  recvB.x = __shfl_xor((int)sendB.x, 32);
  recvB.y = __shfl_xor((int)sendB.y, 32);
  BF8U pB0, pB1;
  if (h32 == 0) {
    pB0.u = (uint4){pg[0].u.x, pg[0].u.y, recvA.x, recvA.y};
    pB1.u = (uint4){pg[2].u.x, pg[2].u.y, recvB.x, recvB.y};
  } else {
    pB0.u = (uint4){recvA.x, recvA.y, pg[1].u.x, pg[1].u.y};
    pB1.u = (uint4){recvB.x, recvB.y, pg[3].u.x, pg[3].u.y};
  }
  pB0v = pB0.v;
  pB1v = pB1.v;
}

// ---- pre-pass: K,V fp32 -> bf16 FRAGMENT-MAJOR 4KB tiles.
// Tile layout (2048 bf16): slot i = chunk(i>>6)*64 + lane(i&63); each slot = 16B.
//   K chunk c, lane l (q32=l&31,h32=l>>5): K[s0+q32][(2c+h32)*8 .. +7]
//   V chunk (s2*2+dt), lane l:            V[s0+8*(2*s2+h32)+j][dt*32+q32], j=0..7
// attn's MFMA operand read is then ONE coalesced 1KB global_load_dwordx4.
// XCD-pinned decode: xcd = bid&7 owns (b,h) pairs [4*xcd, 4*xcd+3].
__global__ __launch_bounds__(256) void prep_kernel(const float* __restrict__ K,
                                                   const float* __restrict__ V,
                                                   __bf16* __restrict__ Kb,
                                                   __bf16* __restrict__ Vb) {
  __shared__ float Vs[32 * 64];
  const int bid = blockIdx.x;
  const int xcd = bid & 7;
  const int idx = bid >> 3;            // 0..255 per XCD
  const int pair = xcd * 4 + (idx >> 6);  // (b*8+h), 4 pairs per XCD
  const int tile = idx & 63;
  const int h = pair & 7;
  const int b = pair >> 3;
  const int obid = pair * 64 + tile;
  const int s0 = tile * 32;
  const int i = threadIdx.x;
  const int chunk = i >> 6;  // 0..3
  const int l = i & 63;
  const int q32 = l & 31;
  const int h32 = l >> 5;

  // K fragment: row q32, cols (2*chunk + h32)*8 .. +7
  {
    const float* src =
        K + (((size_t)(b * S_ + s0 + q32) * H_ + h) * 64 + (2 * chunk + h32) * 8);
    float4 a = *(const float4*)src;
    float4 bb = *(const float4*)(src + 4);
    *(bf16x8*)(Kb + (size_t)obid * TILE_ELEMS + i * 8) = cvt8(a, bb);
  }
  // V rows -> LDS (coalesced), then column-gather into fragments
  {
    const int s = i >> 3, d0 = (i & 7) * 8;
    const float* src = V + (((size_t)(b * S_ + s0 + s) * H_ + h) * 64 + d0);
    float4 a = *(const float4*)src;
    float4 bb = *(const float4*)(src + 4);
    *(float4*)&Vs[s * 64 + d0] = a;
    *(float4*)&Vs[s * 64 + d0 + 4] = bb;
  }
  __syncthreads();
  {
    const int s2 = chunk >> 1, dt = chunk & 1;
    const int d = dt * 32 + q32;
    const int sbase = 8 * (2 * s2 + h32);
    BF8U o;
#pragma unroll
    for (int j = 0; j < 8; ++j) o.v[j] = (__bf16)Vs[(sbase + j) * 64 + d];
    *(bf16x8*)(Vb + (size_t)obid * TILE_ELEMS + i * 8) = o.v;
  }
}

__global__ __launch_bounds__(256, 3) void attn_kernel(const float* __restrict__ Q,
                                                      const __bf16* __restrict__ Kb,
                                                      const __bf16* __restrict__ Vb,
                                                      float* __restrict__ O,
                                                      float* __restrict__ num_ws,
                                                      float* __restrict__ l_ws,
                                                      int splits) {
  // R18: NO __shared__, NO barriers. K/V fragments stream straight from L2.
  const int tid = threadIdx.x;
  const int lane = tid & 63;
  const int wave = tid >> 6;
  const int q32 = lane & 31;
  const int h32 = lane >> 5;

  // ---- XCD-pinned decode: xcd = bid&7; each XCD owns 4 (b,h) pairs.
  const int bid = blockIdx.x;
  const int xcd = bid & 7;
  const int idx = bid >> 3;
  const int bs = 16 * splits;          // tasks per (b,h) pair
  const int pairl = idx / bs;          // 0..3
  const int sub = idx - pairl * bs;    // qb(4) | split
  const int pair = xcd * 4 + pairl;    // (b*8+h)
  const int qb = sub & 15;             // 16 q-blocks of 128 rows
  const int split = sub >> 4;
  const int h = pair & 7;
  const int b = pair >> 3;

  // ---- S-range for this split (splits==3 uneven kept for generality)
  int nt2, tile0;
  if (splits == 3) {
    nt2 = (split < 2) ? 11 : 10;
    tile0 = 22 * split;
  } else {
    nt2 = (S_ / 32) / (2 * splits);
    tile0 = split * 2 * nt2;
  }

  // ---- Q fragments for ONE 32-q group (B-operand: n=q32, k=h32*8+j)
  const float qscale = 0.125f * 1.44269504088896340736f;
  const int qrow = qb * 128 + wave * 32 + q32;
  bf16x8 qf[4];
  {
    const float* qp = Q + ((size_t)(b * L_ + qrow) * H_ + h) * 64;
#pragma unroll
    for (int c = 0; c < 4; ++c) {
      const float* p = qp + c * 16 + h32 * 8;
      float4 a = *(const float4*)p;
      float4 bb = *(const float4*)(p + 4);
      float t[8] = {a.x, a.y, a.z, a.w, bb.x, bb.y, bb.z, bb.w};
#pragma unroll
      for (int j = 0; j < 8; ++j) qf[c][j] = (__bf16)(t[j] * qscale);
    }
  }

  float l = 0.f;
  floatx16 ot[2];  // [d-tile]
#pragma unroll
  for (int r = 0; r < 16; ++r) { ot[0][r] = 0.f; ot[1][r] = 0.f; }

  // Per-lane fragment base: tile t, chunk c lives at  base + t*2048 + c*512 + lane*8.
  const __bf16* KbL = Kb + (size_t)(pair * 64) * TILE_ELEMS + lane * 8;
  const __bf16* VbL = Vb + (size_t)(pair * 64) * TILE_ELEMS + lane * 8;

  for (int t = 0; t < nt2; ++t) {
    const size_t toff = (size_t)(tile0 + 2 * t) * TILE_ELEMS;
    const __bf16* K0 = KbL + toff;
    const __bf16* K1 = K0 + TILE_ELEMS;
    const __bf16* V0 = VbL + toff;
    const __bf16* V1 = V0 + TILE_ELEMS;

    // Issue ALL 16 coalesced fragment loads up front; compiler inserts counted
    // vmcnt waits before first use of each (QK0 waits ~vmcnt(12), PV1 last).
    bf16x8 kA0[4], kA1[4], vA0[4], vA1[4];
#pragma unroll
    for (int c = 0; c < 4; ++c) kA0[c] = *(const bf16x8*)(K0 + c * 512);
#pragma unroll
    for (int c = 0; c < 4; ++c) kA1[c] = *(const bf16x8*)(K1 + c * 512);
#pragma unroll
    for (int c = 0; c < 4; ++c) vA0[c] = *(const bf16x8*)(V0 + c * 512);
#pragma unroll
    for (int c = 0; c < 4; ++c) vA1[c] = *(const bf16x8*)(V1 + c * 512);

    floatx16 sc0;
#pragma unroll
    for (int r = 0; r < 16; ++r) sc0[r] = 0.f;
    __builtin_amdgcn_s_setprio(1);
#pragma unroll
    for (int c = 0; c < 4; ++c)
      sc0 = __builtin_amdgcn_mfma_f32_32x32x16_bf16(kA0[c], qf[c], sc0, 0, 0, 0);
    __builtin_amdgcn_s_setprio(0);

    floatx16 sc1;
#pragma unroll
    for (int r = 0; r < 16; ++r) sc1[r] = 0.f;
    __builtin_amdgcn_s_setprio(1);
#pragma unroll
    for (int c = 0; c < 4; ++c)
      sc1 = __builtin_amdgcn_mfma_f32_32x32x16_bf16(kA1[c], qf[c], sc1, 0, 0, 0);
    __builtin_amdgcn_s_setprio(0);

    bf16x8 p00, p01;
    softmax_pb(sc0, h32, l, p00, p01);
    __builtin_amdgcn_s_setprio(1);
    ot[0] = __builtin_amdgcn_mfma_f32_32x32x16_bf16(vA0[0], p00, ot[0], 0, 0, 0);
    ot[1] = __builtin_amdgcn_mfma_f32_32x32x16_bf16(vA0[1], p00, ot[1], 0, 0, 0);
    ot[0] = __builtin_amdgcn_mfma_f32_32x32x16_bf16(vA0[2], p01, ot[0], 0, 0, 0);
    ot[1] = __builtin_amdgcn_mfma_f32_32x32x16_bf16(vA0[3], p01, ot[1], 0, 0, 0);
    __builtin_amdgcn_s_setprio(0);

    bf16x8 p10, p11;
    softmax_pb(sc1, h32, l, p10, p11);
    __builtin_amdgcn_s_setprio(1);
    ot[0] = __builtin_amdgcn_mfma_f32_32x32x16_bf16(vA1[0], p10, ot[0], 0, 0, 0);
    ot[1] = __builtin_amdgcn_mfma_f32_32x32x16_bf16(vA1[1], p10, ot[1], 0, 0, 0);
    ot[0] = __builtin_amdgcn_mfma_f32_32x32x16_bf16(vA1[2], p11, ot[0], 0, 0, 0);
    ot[1] = __builtin_amdgcn_mfma_f32_32x32x16_bf16(vA1[3], p11, ot[1], 0, 0, 0);
    __builtin_amdgcn_s_setprio(0);
  }

  // ---- epilogue
  {
    float lg = l + __shfl_xor(l, 32);
    if (splits == 1) {
      const float inv = 1.0f / lg;
      float* orow = O + ((size_t)(b * L_ + qrow) * H_ + h) * 64;
#pragma unroll
      for (int dt = 0; dt < 2; ++dt)
#pragma unroll
        for (int gg = 0; gg < 4; ++gg) {
          float4 v = {ot[dt][4 * gg + 0] * inv, ot[dt][4 * gg + 1] * inv,
                      ot[dt][4 * gg + 2] * inv, ot[dt][4 * gg + 3] * inv};
          *(float4*)(orow + dt * 32 + gg * 8 + h32 * 4) = v;
        }
    } else {
      float* nrow =
          num_ws + (size_t)split * NUMSZ + ((size_t)(b * L_ + qrow) * H_ + h) * 64;
#pragma unroll
      for (int dt = 0; dt < 2; ++dt)
#pragma unroll
        for (int gg = 0; gg < 4; ++gg) {
          float4 v = {ot[dt][4 * gg + 0], ot[dt][4 * gg + 1],
                      ot[dt][4 * gg + 2], ot[dt][4 * gg + 3]};
          *(float4*)(nrow + dt * 32 + gg * 8 + h32 * 4) = v;
        }
      if (h32 == 0)
        l_ws[(size_t)split * LSZ + (size_t)(b * L_ + qrow) * H_ + h] = lg;
    }
  }
}

__global__ __launch_bounds__(256) void combine_kernel(const float* __restrict__ num_ws,
                                                      const float* __restrict__ l_ws,
                                                      float* __restrict__ O, int splits) {
  const size_t i4 = ((size_t)blockIdx.x * 256 + threadIdx.x) * 4;
  float4 acc = {0.f, 0.f, 0.f, 0.f};
  float lt = 0.f;
  for (int s = 0; s < splits; ++s) {  // fixed order -> deterministic
    float4 v = *(const float4*)(num_ws + (size_t)s * NUMSZ + i4);
    acc.x += v.x; acc.y += v.y; acc.z += v.z; acc.w += v.w;
    lt += l_ws[(size_t)s * LSZ + (i4 >> 6)];
  }
  const float inv = 1.0f / lt;
  float4 o = {acc.x * inv, acc.y * inv, acc.z * inv, acc.w * inv};
  *(float4*)(O + i4) = o;
}

extern "C" void kernel_launch(void* const* d_in, const int* in_sizes, int n_in,
                              void* d_out, int out_size, void* d_ws, size_t ws_size,
                              hipStream_t stream) {
  const float* Q = (const float*)d_in[0];
  const float* K = (const float*)d_in[1];
  const float* V = (const float*)d_in[2];
  float* O = (float*)d_out;

  __bf16* Kb = (__bf16*)d_ws;
  __bf16* Vb = Kb + KVELEM;
  float* num_ws = (float*)(Vb + KVELEM);
  const size_t base = (size_t)2 * KVELEM * sizeof(__bf16);
  const size_t per_split = ((size_t)NUMSZ + (size_t)LSZ) * sizeof(float);
  int splits = 1;
  if (ws_size >= base + 2 * per_split) splits = 2;  // 1024 blocks; combine ~10us
  float* l_ws = num_ws + (size_t)splits * NUMSZ;

  prep_kernel<<<B_ * H_ * 64, 256, 0, stream>>>(K, V, Kb, Vb);
  dim3 grid(B_ * H_ * 16 * splits);
  attn_kernel<<<grid, 256, 0, stream>>>(Q, Kb, Vb, O, num_ws, l_ws, splits);
  if (splits > 1) {
    combine_kernel<<<NUMSZ / 4 / 256, 256, 0, stream>>>(num_ws, l_ws, O, splits);
  }
}